// Round 3
// baseline (9286.794 us; speedup 1.0000x reference)
//
#include <hip/hip_runtime.h>
#include <stdint.h>
#include <stddef.h>

#define T_ 256
#define H_ 128

typedef __attribute__((ext_vector_type(8))) short short8;
typedef __attribute__((ext_vector_type(4))) float f32x4;

#define MFMA16(a,b,c) __builtin_amdgcn_mfma_f32_16x16x32_bf16(a,b,c,0,0,0)

// ---- ws layout (bytes) ----
#define WS_FL0      0          // flag0[64] @ stride 64
#define WS_FL1      8192       // flag1[64] @ stride 64
#define WS_FLBYTES  16384
#define WS_HTH      16384      // hT hi plane: 512*128 u16
#define WS_HTL      147456     // hT lo plane
#define WS_MB0      278528     // h0 mailbox: per block 4096 B (16x64 u32)
#define WS_MB1      540672     // h1 mailbox
// total ~802816 B

// ---- LDS layouts ----
#define ENC_UH 131072
#define ENC_UL (131072+8448)
#define ENC_SMEM 147968
#define DEC_GX 147968
#define DEC_SMEM (147968+10240)

__device__ __forceinline__ uint16_t bf16rne(float f){
  uint32_t u = __float_as_uint(f);
  uint32_t r = u + 0x7FFFu + ((u >> 16) & 1u);
  return (uint16_t)(r >> 16);
}
__device__ __forceinline__ float fast_sig(float x){
  return __builtin_amdgcn_rcpf(1.0f + __expf(-x));
}
__device__ __forceinline__ float fast_tanh(float x){
  float ax = fabsf(x);
  float e  = __expf(-2.0f * ax);
  float t  = (1.0f - e) * __builtin_amdgcn_rcpf(1.0f + e);
  return copysignf(t, x);
}
__device__ __forceinline__ f32x4 splat4(float v){ f32x4 r={v,v,v,v}; return r; }

// split fp32 -> (bf16 hi, bf16 lo): v ≈ hi + lo to ~2^-17 relative
__device__ __forceinline__ void splitf(float v, uint16_t& h, uint16_t& l){
  h = bf16rne(v);
  float hf = __uint_as_float((uint32_t)h << 16);
  l = bf16rne(v - hf);
}
__device__ __forceinline__ void load_frag2(const float* __restrict__ rowp, int koff,
                                           short8& h, short8& l){
  #pragma unroll
  for(int j=0;j<8;j++){
    uint16_t hb, lb; splitf(rowp[koff+j], hb, lb);
    h[j]=(short)hb; l[j]=(short)lb;
  }
}

__device__ __forceinline__ void waitflag(uint32_t* p, uint32_t want){
  while(__hip_atomic_load(p, __ATOMIC_ACQUIRE, __HIP_MEMORY_SCOPE_AGENT) < want)
    __builtin_amdgcn_s_sleep(8);
}
__device__ __forceinline__ void mstore(uint32_t* p, uint32_t v){
  __hip_atomic_store(p, v, __ATOMIC_RELAXED, __HIP_MEMORY_SCOPE_AGENT);
}
__device__ __forceinline__ uint32_t mload(uint32_t* p){
  return __hip_atomic_load(p, __ATOMIC_RELAXED, __HIP_MEMORY_SCOPE_AGENT);
}

// =====================  ENCODER  =====================
// 32 blocks x 512 thr. Two sequential 1-cell scan phases (layer0, layer1).
// u K-slots: [0,128)=input, [128,256)=h(latest). Split hi/lo planes.
__global__ __launch_bounds__(512,2) void enc_kernel(
    const float* __restrict__ x,
    const float* __restrict__ Wih0, const float* __restrict__ Whh0,
    const float* __restrict__ bih0, const float* __restrict__ bhh0,
    const float* __restrict__ Wih1, const float* __restrict__ Whh1,
    const float* __restrict__ bih1, const float* __restrict__ bhh1,
    uint16_t* __restrict__ plh, uint16_t* __restrict__ pll,   // h0-seq planes (in d_out)
    uint16_t* __restrict__ hTh, uint16_t* __restrict__ hTl)   // final h1 planes (in d_ws)
{
  extern __shared__ __align__(16) char smem[];
  const int tid=threadIdx.x, w=tid>>6, l=tid&63, q=l>>4, m=l&15;
  const int rb = blockIdx.x*16;
  const int colc = w*16+m;
  uint16_t* uh=(uint16_t*)(smem+ENC_UH);
  uint16_t* ul=(uint16_t*)(smem+ENC_UL);
  const int srow=tid>>5, sc4=(tid&31)*4;

  short8 WiH[4][4], WiL[4][4], WhH[4][4];
  float bias[4], c[4];

  auto loadW = [&](const float* Wih,const float* Whh,const float* bi,const float* bh){
    #pragma unroll
    for(int gb=0;gb<4;gb++){
      const int row = gb*128+colc;
      const float* rih = Wih + (size_t)row*128;
      const float* rhh = Whh + (size_t)row*128;
      #pragma unroll
      for(int kt=0;kt<4;kt++){
        load_frag2(rih, kt*32+q*8, WiH[gb][kt], WiL[gb][kt]);
        short8 hh,hl; load_frag2(rhh, kt*32+q*8, hh, hl);
        WhH[gb][kt]=hh;
        *(short8*)(smem + (size_t)(((w*4+gb)*4+kt)*64+l)*16) = hl;
      }
      bias[gb]=bi[row]+bh[row];
    }
  };
  auto zeroH = [&](){
    *(uint64_t*)(uh + srow*264 + 128 + sc4) = 0ull;
    *(uint64_t*)(ul + srow*264 + 128 + sc4) = 0ull;
  };
  auto scat = [&](uint64_t ph, uint64_t pl){
    *(uint64_t*)(uh + srow*264 + sc4) = ph;
    *(uint64_t*)(ul + srow*264 + sc4) = pl;
  };
  auto packf4 = [&](f32x4 v, uint64_t& ph, uint64_t& pl){
    ph=0; pl=0;
    #pragma unroll
    for(int j=0;j<4;j++){
      uint16_t hb,lb; splitf(v[j],hb,lb);
      ph |= (uint64_t)hb << (16*j);
      pl |= (uint64_t)lb << (16*j);
    }
  };

  auto scan = [&](bool first){
    #pragma unroll 1
    for(int t=0;t<T_;t++){
      // prefetch next input slice
      uint64_t nh=0, nl=0;
      const bool dox = (t+1<T_);
      if(dox){
        if(first){
          f32x4 xv = *(const f32x4*)(x + ((size_t)(rb+srow)*T_+(t+1))*128 + sc4);
          packf4(xv, nh, nl);
        } else {
          size_t gi=((size_t)(rb+srow)*T_+(t+1))*128+sc4;
          nh = *(const uint64_t*)(plh+gi);
          nl = *(const uint64_t*)(pll+gi);
        }
      }
      f32x4 acc[4];
      #pragma unroll
      for(int gb=0;gb<4;gb++) acc[gb]=splat4(bias[gb]);
      #pragma unroll
      for(int kt=0;kt<8;kt++){
        short8 Ah = *(const short8*)((char*)uh + m*528 + kt*64 + q*16);
        short8 Al = *(const short8*)((char*)ul + m*528 + kt*64 + q*16);
        #pragma unroll
        for(int gb=0;gb<4;gb++){
          short8 Bh = (kt<4)? WiH[gb][kt] : WhH[gb][kt-4];
          short8 Bl = (kt<4)? WiL[gb][kt]
                            : *(const short8*)(smem + (size_t)(((w*4+gb)*4+(kt-4))*64+l)*16);
          acc[gb]=MFMA16(Ah,Bh,acc[gb]);
          acc[gb]=MFMA16(Ah,Bl,acc[gb]);
          acc[gb]=MFMA16(Al,Bh,acc[gb]);
        }
      }
      __syncthreads();   // MFMA reads of u done -> safe to overwrite
      #pragma unroll
      for(int r=0;r<4;r++){
        float I=fast_sig(acc[0][r]), F=fast_sig(acc[1][r]);
        float G=fast_tanh(acc[2][r]), O=fast_sig(acc[3][r]);
        c[r]=F*c[r]+I*G;
        float hv=O*fast_tanh(c[r]);
        uint16_t hb,lb; splitf(hv,hb,lb);
        const int row=q*4+r;
        uh[row*264+128+colc]=hb; ul[row*264+128+colc]=lb;
        if(first){
          size_t gi=((size_t)(rb+row)*T_+t)*128+colc;
          plh[gi]=hb; pll[gi]=lb;
        } else if(t==T_-1){
          size_t gi=(size_t)(rb+row)*128+colc;
          hTh[gi]=hb; hTl[gi]=lb;
        }
      }
      if(dox) scat(nh,nl);
      __syncthreads();
    }
  };

  // ---- phase A: encoder layer 0 ----
  zeroH();
  { f32x4 v = *(const f32x4*)(x + ((size_t)(rb+srow)*T_+0)*128 + sc4);
    uint64_t ph,pl; packf4(v,ph,pl); scat(ph,pl); }
  loadW(Wih0,Whh0,bih0,bhh0);
  #pragma unroll
  for(int r=0;r<4;r++) c[r]=0.f;
  __syncthreads();
  scan(true);

  // ---- phase B: encoder layer 1 ----
  loadW(Wih1,Whh1,bih1,bhh1);   // prior LDS reads done (scan ends with barrier)
  zeroH();
  { size_t gi=((size_t)(rb+srow)*T_+0)*128+sc4;
    scat(*(const uint64_t*)(plh+gi), *(const uint64_t*)(pll+gi)); }
  #pragma unroll
  for(int r=0;r<4;r++) c[r]=0.f;
  __syncthreads();
  scan(false);
}

// =====================  DECODER  =====================
// 64 blocks = 32 groups x 2 sides. Side s computes h cols [64s,64s+64) of both
// cells; halves exchanged via d_ws mailboxes (agent-scope atomics).
// u K-slots: [0,128)=h1(latest)(=x_in for t>=1; x0 at t=0), [128,256)=h0(latest).
// NOTE: at t=0 the slot [0,128) holds x0=hT which is NOT h1(-1)=0 -> cell1 must
// skip its Whh1 (kt<4) contribution at t=0.
__global__ __launch_bounds__(512,2) void dec_kernel(
    const float* __restrict__ Wih0, const float* __restrict__ Whh0,
    const float* __restrict__ bih0, const float* __restrict__ bhh0,
    const float* __restrict__ Wih1, const float* __restrict__ Whh1,
    const float* __restrict__ bih1, const float* __restrict__ bhh1,
    const uint16_t* __restrict__ hTh, const uint16_t* __restrict__ hTl,
    char* __restrict__ ws, float* __restrict__ out)
{
  extern __shared__ __align__(16) char smem[];
  const int tid=threadIdx.x, w=tid>>6, l=tid&63, q=l>>4, m=l&15;
  const int bid=blockIdx.x, g=bid>>1, s=bid&1, peer=bid^1;
  const int rb=g*16, cb=s*64;
  const int ct=w&3, gblo=(w<4)?0:2;
  uint16_t* uh=(uint16_t*)(smem+ENC_UH);
  uint16_t* ul=(uint16_t*)(smem+ENC_UL);
  char* gx = smem+DEC_GX;
  uint32_t* fl0_own =(uint32_t*)(ws + WS_FL0 + bid*64);
  uint32_t* fl0_peer=(uint32_t*)(ws + WS_FL0 + peer*64);
  uint32_t* fl1_own =(uint32_t*)(ws + WS_FL1 + bid*64);
  uint32_t* fl1_peer=(uint32_t*)(ws + WS_FL1 + peer*64);
  uint32_t* mb0_own =(uint32_t*)(ws + WS_MB0 + bid*4096);
  uint32_t* mb0_peer=(uint32_t*)(ws + WS_MB0 + peer*4096);
  uint32_t* mb1_own =(uint32_t*)(ws + WS_MB1 + bid*4096);
  uint32_t* mb1_peer=(uint32_t*)(ws + WS_MB1 + peer*4096);
  const int pb = 64-cb;   // peer col base

  short8 W0iH[2][4],W0iL[2][4],W0hH[2][4],W0hL[2][4],W1iH[2][4],W1iL[2][4];
  float b0[2], b1[2];
  #pragma unroll
  for(int tt=0;tt<2;tt++){
    const int gb=gblo+tt;
    const int row = gb*128 + cb + ct*16 + m;
    const float* r0i = Wih0 + (size_t)row*128;
    const float* r0h = Whh0 + (size_t)row*128;
    const float* r1i = Wih1 + (size_t)row*128;
    const float* r1h = Whh1 + (size_t)row*128;
    #pragma unroll
    for(int kt=0;kt<4;kt++){
      load_frag2(r0i, kt*32+q*8, W0iH[tt][kt], W0iL[tt][kt]);
      load_frag2(r0h, kt*32+q*8, W0hH[tt][kt], W0hL[tt][kt]);
      load_frag2(r1i, kt*32+q*8, W1iH[tt][kt], W1iL[tt][kt]);
      short8 hh,hl; load_frag2(r1h, kt*32+q*8, hh,hl);
      *(short8*)(smem + (size_t)(((((w*2+tt)*4+kt)*2+0))*64+l)*16)=hh;
      *(short8*)(smem + (size_t)(((((w*2+tt)*4+kt)*2+1))*64+l)*16)=hl;
    }
    b0[tt]=bih0[row]+bhh0[row];
    b1[tt]=bih1[row]+bhh1[row];
  }
  // staging: slots0-3 = hT (x_in(0)), slots4-7 = 0
  {
    const int srow=tid>>5, sc4=(tid&31)*4;
    *(uint64_t*)(uh+srow*264+128+sc4)=0ull;
    *(uint64_t*)(ul+srow*264+128+sc4)=0ull;
    size_t gi=(size_t)(rb+srow)*128+sc4;
    *(uint64_t*)(uh+srow*264+sc4)=*(const uint64_t*)(hTh+gi);
    *(uint64_t*)(ul+srow*264+sc4)=*(const uint64_t*)(hTl+gi);
  }
  float c0[4]={0,0,0,0}, c1[4]={0,0,0,0};

  #pragma unroll 1
  for(int t=0;t<T_;t++){
    if(t>0){
      waitflag(fl1_peer, 4u*(uint32_t)t);
      #pragma unroll
      for(int i=0;i<2;i++){
        int idx=tid*2+i, row=idx>>6, col=idx&63;
        uint32_t v=mload(mb1_peer+idx);
        uh[row*264+pb+col]=(uint16_t)(v>>16); ul[row*264+pb+col]=(uint16_t)v;
      }
    }
    __syncthreads();                       // B1: u=[x_in|h0(t-1)] complete
    // ---- cell0 ----
    f32x4 acc[2];
    acc[0]=splat4(b0[0]); acc[1]=splat4(b0[1]);
    #pragma unroll
    for(int kt=0;kt<8;kt++){
      short8 Ah=*(const short8*)((char*)uh+m*528+kt*64+q*16);
      short8 Al=*(const short8*)((char*)ul+m*528+kt*64+q*16);
      #pragma unroll
      for(int tt=0;tt<2;tt++){
        short8 Bh=(kt<4)?W0iH[tt][kt]:W0hH[tt][kt-4];
        short8 Bl=(kt<4)?W0iL[tt][kt]:W0hL[tt][kt-4];
        acc[tt]=MFMA16(Ah,Bh,acc[tt]);
        acc[tt]=MFMA16(Ah,Bl,acc[tt]);
        acc[tt]=MFMA16(Al,Bh,acc[tt]);
      }
    }
    if(w>=4){
      #pragma unroll
      for(int tt=0;tt<2;tt++)
        *(f32x4*)(gx + ((ct*2+tt)*16+m)*80 + q*16) = acc[tt];
    }
    __syncthreads();                       // B2: gx visible, cell0 u-reads done
    if(w<4){
      f32x4 gg=*(const f32x4*)(gx + ((ct*2+0)*16+m)*80 + q*16);
      f32x4 go=*(const f32x4*)(gx + ((ct*2+1)*16+m)*80 + q*16);
      const int lc=ct*16+m, gc=cb+lc;
      #pragma unroll
      for(int r=0;r<4;r++){
        float I=fast_sig(acc[0][r]), F=fast_sig(acc[1][r]);
        float G=fast_tanh(gg[r]),    O=fast_sig(go[r]);
        c0[r]=F*c0[r]+I*G;
        float hv=O*fast_tanh(c0[r]);
        uint16_t hb,lb; splitf(hv,hb,lb);
        const int row=q*4+r;
        uh[row*264+128+gc]=hb; ul[row*264+128+gc]=lb;
        mstore(mb0_own + row*64 + lc, ((uint32_t)hb<<16)|lb);
      }
      if(l==0) __hip_atomic_fetch_add(fl0_own,1u,__ATOMIC_RELEASE,__HIP_MEMORY_SCOPE_AGENT);
    }
    waitflag(fl0_peer, 4u*(uint32_t)(t+1));
    #pragma unroll
    for(int i=0;i<2;i++){
      int idx=tid*2+i, row=idx>>6, col=idx&63;
      uint32_t v=mload(mb0_peer+idx);
      uh[row*264+128+pb+col]=(uint16_t)(v>>16); ul[row*264+128+pb+col]=(uint16_t)v;
    }
    __syncthreads();                       // B3: u=[h1(t-1)|h0(t)] complete
    // ---- cell1 ----
    acc[0]=splat4(b1[0]); acc[1]=splat4(b1[1]);
    #pragma unroll
    for(int kt=0;kt<8;kt++){
      if(kt<4 && t==0) continue;   // h1(-1)=0: slot holds x0, skip Whh1 term (FIX)
      short8 Ah=*(const short8*)((char*)uh+m*528+kt*64+q*16);
      short8 Al=*(const short8*)((char*)ul+m*528+kt*64+q*16);
      #pragma unroll
      for(int tt=0;tt<2;tt++){
        short8 Bh,Bl;
        if(kt<4){
          Bh=*(const short8*)(smem + (size_t)(((((w*2+tt)*4+kt)*2+0))*64+l)*16);
          Bl=*(const short8*)(smem + (size_t)(((((w*2+tt)*4+kt)*2+1))*64+l)*16);
        } else { Bh=W1iH[tt][kt-4]; Bl=W1iL[tt][kt-4]; }
        acc[tt]=MFMA16(Ah,Bh,acc[tt]);
        acc[tt]=MFMA16(Ah,Bl,acc[tt]);
        acc[tt]=MFMA16(Al,Bh,acc[tt]);
      }
    }
    if(w>=4){
      #pragma unroll
      for(int tt=0;tt<2;tt++)
        *(f32x4*)(gx + ((ct*2+tt)*16+m)*80 + q*16) = acc[tt];
    }
    __syncthreads();                       // B4: gx visible, cell1 u-reads done
    if(w<4){
      f32x4 gg=*(const f32x4*)(gx + ((ct*2+0)*16+m)*80 + q*16);
      f32x4 go=*(const f32x4*)(gx + ((ct*2+1)*16+m)*80 + q*16);
      const int lc=ct*16+m, gc=cb+lc;
      #pragma unroll
      for(int r=0;r<4;r++){
        float I=fast_sig(acc[0][r]), F=fast_sig(acc[1][r]);
        float G=fast_tanh(gg[r]),    O=fast_sig(go[r]);
        c1[r]=F*c1[r]+I*G;
        float hv=O*fast_tanh(c1[r]);
        uint16_t hb,lb; splitf(hv,hb,lb);
        const int row=q*4+r;
        uh[row*264+gc]=hb; ul[row*264+gc]=lb;
        mstore(mb1_own + row*64 + lc, ((uint32_t)hb<<16)|lb);
        out[((size_t)(rb+row)*T_+t)*128+gc]=hv;
      }
      if(l==0) __hip_atomic_fetch_add(fl1_own,1u,__ATOMIC_RELEASE,__HIP_MEMORY_SCOPE_AGENT);
    }
  }
}

// =====================  OUTPUT PROJECTION  =====================
// In-place: out[n,:] = split(out[n,:]) @ split(out_W)^T + out_b. 512 blk x 256 thr.
__global__ __launch_bounds__(256,2) void outproj_kernel(
    const float* __restrict__ oW, const float* __restrict__ ob,
    float* __restrict__ out)
{
  __shared__ float As[16*132];
  const int tid=threadIdx.x, w=tid>>6, l=tid&63, q=l>>4, m=l&15;

  short8 BH[2][4], BL[2][4];
  float bias[2];
  #pragma unroll
  for(int tt=0;tt<2;tt++){
    const int j = (w*2+tt)*16+m;
    const float* rowp = oW + (size_t)j*128;
    #pragma unroll
    for(int kt=0;kt<4;kt++) load_frag2(rowp, kt*32+q*8, BH[tt][kt], BL[tt][kt]);
    bias[tt]=ob[j];
  }

  for(int s16=0;s16<16;s16++){
    const int strip = blockIdx.x*16 + s16;
    {
      const int row=tid>>4, col=(tid&15)*8;
      const float* src = out + ((size_t)strip*16+row)*128 + col;
      f32x4 a=*(const f32x4*)src, b=*(const f32x4*)(src+4);
      *(f32x4*)(As+row*132+col)=a; *(f32x4*)(As+row*132+col+4)=b;
    }
    __syncthreads();
    short8 Ah[4], Al[4];
    #pragma unroll
    for(int kt=0;kt<4;kt++){
      #pragma unroll
      for(int j=0;j<8;j++){
        uint16_t hb,lb; splitf(As[m*132+kt*32+q*8+j],hb,lb);
        Ah[kt][j]=(short)hb; Al[kt][j]=(short)lb;
      }
    }
    __syncthreads();
    f32x4 acc[2];
    acc[0]=splat4(bias[0]); acc[1]=splat4(bias[1]);
    #pragma unroll
    for(int kt=0;kt<4;kt++){
      #pragma unroll
      for(int tt=0;tt<2;tt++){
        acc[tt]=MFMA16(Ah[kt],BH[tt][kt],acc[tt]);
        acc[tt]=MFMA16(Ah[kt],BL[tt][kt],acc[tt]);
        acc[tt]=MFMA16(Al[kt],BH[tt][kt],acc[tt]);
      }
    }
    #pragma unroll
    for(int tt=0;tt<2;tt++){
      const int col = w*32+tt*16+m;
      #pragma unroll
      for(int r=0;r<4;r++)
        out[((size_t)strip*16+q*4+r)*128+col]=acc[tt][r];
    }
  }
}

extern "C" void kernel_launch(void* const* d_in, const int* in_sizes, int n_in,
                              void* d_out, int out_size, void* d_ws, size_t ws_size,
                              hipStream_t stream) {
  const float* x     = (const float*)d_in[0];
  const float* eWih0 = (const float*)d_in[1];
  const float* eWhh0 = (const float*)d_in[2];
  const float* ebih0 = (const float*)d_in[3];
  const float* ebhh0 = (const float*)d_in[4];
  const float* eWih1 = (const float*)d_in[5];
  const float* eWhh1 = (const float*)d_in[6];
  const float* ebih1 = (const float*)d_in[7];
  const float* ebhh1 = (const float*)d_in[8];
  const float* dWih0 = (const float*)d_in[9];
  const float* dWhh0 = (const float*)d_in[10];
  const float* dbih0 = (const float*)d_in[11];
  const float* dbhh0 = (const float*)d_in[12];
  const float* dWih1 = (const float*)d_in[13];
  const float* dWhh1 = (const float*)d_in[14];
  const float* dbih1 = (const float*)d_in[15];
  const float* dbhh1 = (const float*)d_in[16];
  const float* oW    = (const float*)d_in[17];
  const float* ob    = (const float*)d_in[18];
  float* out = (float*)d_out;
  char* ws = (char*)d_ws;

  (void)hipFuncSetAttribute((const void*)enc_kernel,
        hipFuncAttributeMaxDynamicSharedMemorySize, ENC_SMEM);
  (void)hipFuncSetAttribute((const void*)dec_kernel,
        hipFuncAttributeMaxDynamicSharedMemorySize, DEC_SMEM);

  // reset decoder flags
  hipMemsetAsync(d_ws, 0, WS_FLBYTES, stream);

  uint16_t* plh = (uint16_t*)d_out;
  uint16_t* pll = plh + (size_t)512*T_*H_;
  uint16_t* hTh = (uint16_t*)(ws + WS_HTH);
  uint16_t* hTl = (uint16_t*)(ws + WS_HTL);

  enc_kernel<<<32, 512, ENC_SMEM, stream>>>(
      x, eWih0, eWhh0, ebih0, ebhh0, eWih1, eWhh1, ebih1, ebhh1,
      plh, pll, hTh, hTl);
  dec_kernel<<<64, 512, DEC_SMEM, stream>>>(
      dWih0, dWhh0, dbih0, dbhh0, dWih1, dWhh1, dbih1, dbhh1,
      hTh, hTl, ws, out);
  outproj_kernel<<<512, 256, 0, stream>>>(oW, ob, out);
}

// Round 4
// 3698.040 us; speedup vs baseline: 2.5113x; 2.5113x over previous
//
#include <hip/hip_runtime.h>
#include <stdint.h>
#include <stddef.h>

#define T_ 256
#define H_ 128

typedef __attribute__((ext_vector_type(8))) short short8;
typedef __attribute__((ext_vector_type(4))) float f32x4;

#define MFMA16(a,b,c) __builtin_amdgcn_mfma_f32_16x16x32_bf16(a,b,c,0,0,0)

// ---- ws layout (bytes) ----
// Tagged mailboxes (zeroed each launch by in-stream memset; harness poisons ws
// with 0xAA and tag==t+1 polling must never false-match).
#define WS_MB0      0            // 64 blocks * 8192 B (16x64 u64)
#define WS_MB1      524288       // 64 blocks * 8192 B
#define WS_MB_BYTES 1048576
#define WS_HTH      1048576      // hT hi plane: 512*128 u16
#define WS_HTL      (1048576+131072)
// total 1310720 B

// ---- LDS layouts ----
#define ENC_UH 131072
#define ENC_UL (131072+8448)
#define ENC_SMEM 147968
#define DEC_GX 147968
#define DEC_SMEM (147968+10240)

__device__ __forceinline__ uint16_t bf16rne(float f){
  uint32_t u = __float_as_uint(f);
  uint32_t r = u + 0x7FFFu + ((u >> 16) & 1u);
  return (uint16_t)(r >> 16);
}
__device__ __forceinline__ float fast_sig(float x){
  return __builtin_amdgcn_rcpf(1.0f + __expf(-x));
}
__device__ __forceinline__ float fast_tanh(float x){
  float ax = fabsf(x);
  float e  = __expf(-2.0f * ax);
  float t  = (1.0f - e) * __builtin_amdgcn_rcpf(1.0f + e);
  return copysignf(t, x);
}
__device__ __forceinline__ f32x4 splat4(float v){ f32x4 r={v,v,v,v}; return r; }

// split fp32 -> (bf16 hi, bf16 lo): v ~= hi + lo to ~2^-17 relative
__device__ __forceinline__ void splitf(float v, uint16_t& h, uint16_t& l){
  h = bf16rne(v);
  float hf = __uint_as_float((uint32_t)h << 16);
  l = bf16rne(v - hf);
}
__device__ __forceinline__ void load_frag2(const float* __restrict__ rowp, int koff,
                                           short8& h, short8& l){
  #pragma unroll
  for(int j=0;j<8;j++){
    uint16_t hb, lb; splitf(rowp[koff+j], hb, lb);
    h[j]=(short)hb; l[j]=(short)lb;
  }
}

// =====================  ENCODER  =====================
// 32 blocks x 512 thr (1 block/CU, 2 waves/SIMD, 256-VGPR budget -> no spills).
// Two sequential 1-cell scan phases. u K-slots: [0,128)=input, [128,256)=h.
__global__ __launch_bounds__(512,1) void enc_kernel(
    const float* __restrict__ x,
    const float* __restrict__ Wih0, const float* __restrict__ Whh0,
    const float* __restrict__ bih0, const float* __restrict__ bhh0,
    const float* __restrict__ Wih1, const float* __restrict__ Whh1,
    const float* __restrict__ bih1, const float* __restrict__ bhh1,
    uint16_t* __restrict__ plh, uint16_t* __restrict__ pll,   // h0-seq planes (in d_out)
    uint16_t* __restrict__ hTh, uint16_t* __restrict__ hTl)   // final h1 planes (in d_ws)
{
  extern __shared__ __align__(16) char smem[];
  const int tid=threadIdx.x, w=tid>>6, l=tid&63, q=l>>4, m=l&15;
  const int rb = blockIdx.x*16;
  const int colc = w*16+m;
  uint16_t* uh=(uint16_t*)(smem+ENC_UH);
  uint16_t* ul=(uint16_t*)(smem+ENC_UL);
  const int srow=tid>>5, sc4=(tid&31)*4;

  short8 WiH[4][4], WiL[4][4], WhH[4][4];
  float bias[4], c[4];

  auto loadW = [&](const float* Wih,const float* Whh,const float* bi,const float* bh){
    #pragma unroll
    for(int gb=0;gb<4;gb++){
      const int row = gb*128+colc;
      const float* rih = Wih + (size_t)row*128;
      const float* rhh = Whh + (size_t)row*128;
      #pragma unroll
      for(int kt=0;kt<4;kt++){
        load_frag2(rih, kt*32+q*8, WiH[gb][kt], WiL[gb][kt]);
        short8 hh,hl; load_frag2(rhh, kt*32+q*8, hh, hl);
        WhH[gb][kt]=hh;
        *(short8*)(smem + (size_t)(((w*4+gb)*4+kt)*64+l)*16) = hl;
      }
      bias[gb]=bi[row]+bh[row];
    }
  };
  auto zeroH = [&](){
    *(uint64_t*)(uh + srow*264 + 128 + sc4) = 0ull;
    *(uint64_t*)(ul + srow*264 + 128 + sc4) = 0ull;
  };
  auto scat = [&](uint64_t ph, uint64_t pl){
    *(uint64_t*)(uh + srow*264 + sc4) = ph;
    *(uint64_t*)(ul + srow*264 + sc4) = pl;
  };
  auto packf4 = [&](f32x4 v, uint64_t& ph, uint64_t& pl){
    ph=0; pl=0;
    #pragma unroll
    for(int j=0;j<4;j++){
      uint16_t hb,lb; splitf(v[j],hb,lb);
      ph |= (uint64_t)hb << (16*j);
      pl |= (uint64_t)lb << (16*j);
    }
  };

  auto scan = [&](bool first){
    #pragma unroll 1
    for(int t=0;t<T_;t++){
      uint64_t nh=0, nl=0;
      const bool dox = (t+1<T_);
      if(dox){
        if(first){
          f32x4 xv = *(const f32x4*)(x + ((size_t)(rb+srow)*T_+(t+1))*128 + sc4);
          packf4(xv, nh, nl);
        } else {
          size_t gi=((size_t)(rb+srow)*T_+(t+1))*128+sc4;
          nh = *(const uint64_t*)(plh+gi);
          nl = *(const uint64_t*)(pll+gi);
        }
      }
      f32x4 acc[4];
      #pragma unroll
      for(int gb=0;gb<4;gb++) acc[gb]=splat4(bias[gb]);
      #pragma unroll
      for(int kt=0;kt<8;kt++){
        short8 Ah = *(const short8*)((char*)uh + m*528 + kt*64 + q*16);
        short8 Al = *(const short8*)((char*)ul + m*528 + kt*64 + q*16);
        #pragma unroll
        for(int gb=0;gb<4;gb++){
          short8 Bh = (kt<4)? WiH[gb][kt] : WhH[gb][kt-4];
          short8 Bl = (kt<4)? WiL[gb][kt]
                            : *(const short8*)(smem + (size_t)(((w*4+gb)*4+(kt-4))*64+l)*16);
          acc[gb]=MFMA16(Ah,Bh,acc[gb]);
          acc[gb]=MFMA16(Ah,Bl,acc[gb]);
          acc[gb]=MFMA16(Al,Bh,acc[gb]);
        }
      }
      __syncthreads();   // MFMA reads of u done -> safe to overwrite
      #pragma unroll
      for(int r=0;r<4;r++){
        float I=fast_sig(acc[0][r]), F=fast_sig(acc[1][r]);
        float G=fast_tanh(acc[2][r]), O=fast_sig(acc[3][r]);
        c[r]=F*c[r]+I*G;
        float hv=O*fast_tanh(c[r]);
        uint16_t hb,lb; splitf(hv,hb,lb);
        const int row=q*4+r;
        uh[row*264+128+colc]=hb; ul[row*264+128+colc]=lb;
        if(first){
          size_t gi=((size_t)(rb+row)*T_+t)*128+colc;
          plh[gi]=hb; pll[gi]=lb;
        } else if(t==T_-1){
          size_t gi=(size_t)(rb+row)*128+colc;
          hTh[gi]=hb; hTl[gi]=lb;
        }
      }
      if(dox) scat(nh,nl);
      __syncthreads();
    }
  };

  // ---- phase A: encoder layer 0 ----
  zeroH();
  { f32x4 v = *(const f32x4*)(x + ((size_t)(rb+srow)*T_+0)*128 + sc4);
    uint64_t ph,pl; packf4(v,ph,pl); scat(ph,pl); }
  loadW(Wih0,Whh0,bih0,bhh0);
  #pragma unroll
  for(int r=0;r<4;r++) c[r]=0.f;
  __syncthreads();
  scan(true);

  // ---- phase B: encoder layer 1 ----
  loadW(Wih1,Whh1,bih1,bhh1);
  zeroH();
  { size_t gi=((size_t)(rb+srow)*T_+0)*128+sc4;
    scat(*(const uint64_t*)(plh+gi), *(const uint64_t*)(pll+gi)); }
  #pragma unroll
  for(int r=0;r<4;r++) c[r]=0.f;
  __syncthreads();
  scan(false);
}

// =====================  DECODER  =====================
// 64 blocks = 32 groups x 2 sides (1 block/CU). Side s computes h cols
// [64s,64s+64) of both cells; halves exchanged via TAGGED u64 mailboxes:
//   word = (tag=t+1)<<32 | hb<<16 | lb, written with atomicExch (device
//   coherence point, no cache flush), polled with atomicAdd(p,0) until
//   tag == t+1. Per-direction buffers; tags monotonic; slot written once/step.
// u K-slots: [0,128)=h1(latest)(=x_in; x0 at t=0), [128,256)=h0(latest).
// At t=0 cell1 must skip its Whh1 (kt<4) term: h1(-1)=0 but slot holds x0.
__global__ __launch_bounds__(512,1) void dec_kernel(
    const float* __restrict__ Wih0, const float* __restrict__ Whh0,
    const float* __restrict__ bih0, const float* __restrict__ bhh0,
    const float* __restrict__ Wih1, const float* __restrict__ Whh1,
    const float* __restrict__ bih1, const float* __restrict__ bhh1,
    const uint16_t* __restrict__ hTh, const uint16_t* __restrict__ hTl,
    char* __restrict__ ws, float* __restrict__ out)
{
  extern __shared__ __align__(16) char smem[];
  const int tid=threadIdx.x, w=tid>>6, l=tid&63, q=l>>4, m=l&15;
  const int bid=blockIdx.x, g=bid>>1, s=bid&1, peer=bid^1;
  const int rb=g*16, cb=s*64;
  const int ct=w&3, gblo=(w<4)?0:2;
  uint16_t* uh=(uint16_t*)(smem+ENC_UH);
  uint16_t* ul=(uint16_t*)(smem+ENC_UL);
  char* gx = smem+DEC_GX;
  unsigned long long* mb0_own =(unsigned long long*)(ws + WS_MB0 + bid*8192);
  unsigned long long* mb0_peer=(unsigned long long*)(ws + WS_MB0 + peer*8192);
  unsigned long long* mb1_own =(unsigned long long*)(ws + WS_MB1 + bid*8192);
  unsigned long long* mb1_peer=(unsigned long long*)(ws + WS_MB1 + peer*8192);
  const int pb = 64-cb;   // peer col base

  short8 W0iH[2][4],W0iL[2][4],W0hH[2][4],W0hL[2][4],W1iH[2][4],W1iL[2][4];
  float b0[2], b1[2];
  #pragma unroll
  for(int tt=0;tt<2;tt++){
    const int gb=gblo+tt;
    const int row = gb*128 + cb + ct*16 + m;
    const float* r0i = Wih0 + (size_t)row*128;
    const float* r0h = Whh0 + (size_t)row*128;
    const float* r1i = Wih1 + (size_t)row*128;
    const float* r1h = Whh1 + (size_t)row*128;
    #pragma unroll
    for(int kt=0;kt<4;kt++){
      load_frag2(r0i, kt*32+q*8, W0iH[tt][kt], W0iL[tt][kt]);
      load_frag2(r0h, kt*32+q*8, W0hH[tt][kt], W0hL[tt][kt]);
      load_frag2(r1i, kt*32+q*8, W1iH[tt][kt], W1iL[tt][kt]);
      short8 hh,hl; load_frag2(r1h, kt*32+q*8, hh,hl);
      *(short8*)(smem + (size_t)(((((w*2+tt)*4+kt)*2+0))*64+l)*16)=hh;
      *(short8*)(smem + (size_t)(((((w*2+tt)*4+kt)*2+1))*64+l)*16)=hl;
    }
    b0[tt]=bih0[row]+bhh0[row];
    b1[tt]=bih1[row]+bhh1[row];
  }
  // staging: slots0-3 = hT (x_in(0)), slots4-7 = 0
  {
    const int srow=tid>>5, sc4=(tid&31)*4;
    *(uint64_t*)(uh+srow*264+128+sc4)=0ull;
    *(uint64_t*)(ul+srow*264+128+sc4)=0ull;
    size_t gi=(size_t)(rb+srow)*128+sc4;
    *(uint64_t*)(uh+srow*264+sc4)=*(const uint64_t*)(hTh+gi);
    *(uint64_t*)(ul+srow*264+sc4)=*(const uint64_t*)(hTl+gi);
  }
  float c0[4]={0,0,0,0}, c1[4]={0,0,0,0};

  #pragma unroll 1
  for(int t=0;t<T_;t++){
    if(t>0){
      // ingest peer h1(t-1): tag == t (written at step t-1)
      #pragma unroll
      for(int i=0;i<2;i++){
        int idx=tid*2+i, row=idx>>6, col=idx&63;
        unsigned long long v;
        do { v = atomicAdd(mb1_peer+idx, 0ull);
             if((unsigned)(v>>32) == (unsigned)t) break;
             __builtin_amdgcn_s_sleep(1);
        } while(true);
        uh[row*264+pb+col]=(uint16_t)(v>>16); ul[row*264+pb+col]=(uint16_t)v;
      }
    }
    __syncthreads();                       // B1: u=[x_in|h0(t-1)] complete
    // ---- cell0 ----
    f32x4 acc[2];
    acc[0]=splat4(b0[0]); acc[1]=splat4(b0[1]);
    #pragma unroll
    for(int kt=0;kt<8;kt++){
      short8 Ah=*(const short8*)((char*)uh+m*528+kt*64+q*16);
      short8 Al=*(const short8*)((char*)ul+m*528+kt*64+q*16);
      #pragma unroll
      for(int tt=0;tt<2;tt++){
        short8 Bh=(kt<4)?W0iH[tt][kt]:W0hH[tt][kt-4];
        short8 Bl=(kt<4)?W0iL[tt][kt]:W0hL[tt][kt-4];
        acc[tt]=MFMA16(Ah,Bh,acc[tt]);
        acc[tt]=MFMA16(Ah,Bl,acc[tt]);
        acc[tt]=MFMA16(Al,Bh,acc[tt]);
      }
    }
    if(w>=4){
      #pragma unroll
      for(int tt=0;tt<2;tt++)
        *(f32x4*)(gx + ((ct*2+tt)*16+m)*80 + q*16) = acc[tt];
    }
    __syncthreads();                       // B2: gx visible, cell0 u-reads done
    if(w<4){
      f32x4 gg=*(const f32x4*)(gx + ((ct*2+0)*16+m)*80 + q*16);
      f32x4 go=*(const f32x4*)(gx + ((ct*2+1)*16+m)*80 + q*16);
      const int lc=ct*16+m, gc=cb+lc;
      #pragma unroll
      for(int r=0;r<4;r++){
        float I=fast_sig(acc[0][r]), F=fast_sig(acc[1][r]);
        float G=fast_tanh(gg[r]),    O=fast_sig(go[r]);
        c0[r]=F*c0[r]+I*G;
        float hv=O*fast_tanh(c0[r]);
        uint16_t hb,lb; splitf(hv,hb,lb);
        const int row=q*4+r;
        uh[row*264+128+gc]=hb; ul[row*264+128+gc]=lb;
        unsigned long long tv = ((unsigned long long)(unsigned)(t+1)<<32)
                              | ((unsigned)hb<<16) | (unsigned)lb;
        atomicExch(mb0_own + row*64 + lc, tv);
      }
    }
    // ingest peer h0(t): tag == t+1
    #pragma unroll
    for(int i=0;i<2;i++){
      int idx=tid*2+i, row=idx>>6, col=idx&63;
      unsigned long long v;
      do { v = atomicAdd(mb0_peer+idx, 0ull);
           if((unsigned)(v>>32) == (unsigned)(t+1)) break;
           __builtin_amdgcn_s_sleep(1);
      } while(true);
      uh[row*264+128+pb+col]=(uint16_t)(v>>16); ul[row*264+128+pb+col]=(uint16_t)v;
    }
    __syncthreads();                       // B3: u=[h1(t-1)|h0(t)] complete
    // ---- cell1 ----
    acc[0]=splat4(b1[0]); acc[1]=splat4(b1[1]);
    #pragma unroll
    for(int kt=0;kt<8;kt++){
      if(kt<4 && t==0) continue;   // h1(-1)=0: slot holds x0, skip Whh1 term
      short8 Ah=*(const short8*)((char*)uh+m*528+kt*64+q*16);
      short8 Al=*(const short8*)((char*)ul+m*528+kt*64+q*16);
      #pragma unroll
      for(int tt=0;tt<2;tt++){
        short8 Bh,Bl;
        if(kt<4){
          Bh=*(const short8*)(smem + (size_t)(((((w*2+tt)*4+kt)*2+0))*64+l)*16);
          Bl=*(const short8*)(smem + (size_t)(((((w*2+tt)*4+kt)*2+1))*64+l)*16);
        } else { Bh=W1iH[tt][kt-4]; Bl=W1iL[tt][kt-4]; }
        acc[tt]=MFMA16(Ah,Bh,acc[tt]);
        acc[tt]=MFMA16(Ah,Bl,acc[tt]);
        acc[tt]=MFMA16(Al,Bh,acc[tt]);
      }
    }
    if(w>=4){
      #pragma unroll
      for(int tt=0;tt<2;tt++)
        *(f32x4*)(gx + ((ct*2+tt)*16+m)*80 + q*16) = acc[tt];
    }
    __syncthreads();                       // B4: gx visible, cell1 u-reads done
    if(w<4){
      f32x4 gg=*(const f32x4*)(gx + ((ct*2+0)*16+m)*80 + q*16);
      f32x4 go=*(const f32x4*)(gx + ((ct*2+1)*16+m)*80 + q*16);
      const int lc=ct*16+m, gc=cb+lc;
      #pragma unroll
      for(int r=0;r<4;r++){
        float I=fast_sig(acc[0][r]), F=fast_sig(acc[1][r]);
        float G=fast_tanh(gg[r]),    O=fast_sig(go[r]);
        c1[r]=F*c1[r]+I*G;
        float hv=O*fast_tanh(c1[r]);
        uint16_t hb,lb; splitf(hv,hb,lb);
        const int row=q*4+r;
        uh[row*264+gc]=hb; ul[row*264+gc]=lb;
        unsigned long long tv = ((unsigned long long)(unsigned)(t+1)<<32)
                              | ((unsigned)hb<<16) | (unsigned)lb;
        atomicExch(mb1_own + row*64 + lc, tv);
        out[((size_t)(rb+row)*T_+t)*128+gc]=hv;
      }
    }
  }
}

// =====================  OUTPUT PROJECTION  =====================
__global__ __launch_bounds__(256,2) void outproj_kernel(
    const float* __restrict__ oW, const float* __restrict__ ob,
    float* __restrict__ out)
{
  __shared__ float As[16*132];
  const int tid=threadIdx.x, w=tid>>6, l=tid&63, q=l>>4, m=l&15;

  short8 BH[2][4], BL[2][4];
  float bias[2];
  #pragma unroll
  for(int tt=0;tt<2;tt++){
    const int j = (w*2+tt)*16+m;
    const float* rowp = oW + (size_t)j*128;
    #pragma unroll
    for(int kt=0;kt<4;kt++) load_frag2(rowp, kt*32+q*8, BH[tt][kt], BL[tt][kt]);
    bias[tt]=ob[j];
  }

  for(int s16=0;s16<16;s16++){
    const int strip = blockIdx.x*16 + s16;
    {
      const int row=tid>>4, col=(tid&15)*8;
      const float* src = out + ((size_t)strip*16+row)*128 + col;
      f32x4 a=*(const f32x4*)src, b=*(const f32x4*)(src+4);
      *(f32x4*)(As+row*132+col)=a; *(f32x4*)(As+row*132+col+4)=b;
    }
    __syncthreads();
    short8 Ah[4], Al[4];
    #pragma unroll
    for(int kt=0;kt<4;kt++){
      #pragma unroll
      for(int j=0;j<8;j++){
        uint16_t hb,lb; splitf(As[m*132+kt*32+q*8+j],hb,lb);
        Ah[kt][j]=(short)hb; Al[kt][j]=(short)lb;
      }
    }
    __syncthreads();
    f32x4 acc[2];
    acc[0]=splat4(bias[0]); acc[1]=splat4(bias[1]);
    #pragma unroll
    for(int kt=0;kt<4;kt++){
      #pragma unroll
      for(int tt=0;tt<2;tt++){
        acc[tt]=MFMA16(Ah[kt],BH[tt][kt],acc[tt]);
        acc[tt]=MFMA16(Ah[kt],BL[tt][kt],acc[tt]);
        acc[tt]=MFMA16(Al[kt],BH[tt][kt],acc[tt]);
      }
    }
    #pragma unroll
    for(int tt=0;tt<2;tt++){
      const int col = w*32+tt*16+m;
      #pragma unroll
      for(int r=0;r<4;r++)
        out[((size_t)strip*16+q*4+r)*128+col]=acc[tt][r];
    }
  }
}

extern "C" void kernel_launch(void* const* d_in, const int* in_sizes, int n_in,
                              void* d_out, int out_size, void* d_ws, size_t ws_size,
                              hipStream_t stream) {
  const float* x     = (const float*)d_in[0];
  const float* eWih0 = (const float*)d_in[1];
  const float* eWhh0 = (const float*)d_in[2];
  const float* ebih0 = (const float*)d_in[3];
  const float* ebhh0 = (const float*)d_in[4];
  const float* eWih1 = (const float*)d_in[5];
  const float* eWhh1 = (const float*)d_in[6];
  const float* ebih1 = (const float*)d_in[7];
  const float* ebhh1 = (const float*)d_in[8];
  const float* dWih0 = (const float*)d_in[9];
  const float* dWhh0 = (const float*)d_in[10];
  const float* dbih0 = (const float*)d_in[11];
  const float* dbhh0 = (const float*)d_in[12];
  const float* dWih1 = (const float*)d_in[13];
  const float* dWhh1 = (const float*)d_in[14];
  const float* dbih1 = (const float*)d_in[15];
  const float* dbhh1 = (const float*)d_in[16];
  const float* oW    = (const float*)d_in[17];
  const float* ob    = (const float*)d_in[18];
  float* out = (float*)d_out;
  char* ws = (char*)d_ws;

  (void)hipFuncSetAttribute((const void*)enc_kernel,
        hipFuncAttributeMaxDynamicSharedMemorySize, ENC_SMEM);
  (void)hipFuncSetAttribute((const void*)dec_kernel,
        hipFuncAttributeMaxDynamicSharedMemorySize, DEC_SMEM);

  // zero the tagged mailboxes (ws is poisoned 0xAA before every launch)
  hipMemsetAsync(d_ws, 0, WS_MB_BYTES, stream);

  uint16_t* plh = (uint16_t*)d_out;
  uint16_t* pll = plh + (size_t)512*T_*H_;
  uint16_t* hTh = (uint16_t*)(ws + WS_HTH);
  uint16_t* hTl = (uint16_t*)(ws + WS_HTL);

  enc_kernel<<<32, 512, ENC_SMEM, stream>>>(
      x, eWih0, eWhh0, ebih0, ebhh0, eWih1, eWhh1, ebih1, ebhh1,
      plh, pll, hTh, hTl);
  dec_kernel<<<64, 512, DEC_SMEM, stream>>>(
      dWih0, dWhh0, dbih0, dbhh0, dWih1, dWhh1, dbih1, dbhh1,
      hTh, hTl, ws, out);
  outproj_kernel<<<512, 256, 0, stream>>>(oW, ob, out);
}